// Round 13
// baseline (133.511 us; speedup 1.0000x reference)
//
#include <hip/hip_runtime.h>

#define BB 2
#define HH 1024
#define WW 1024
#define MU 5

// fused-pass tile geometry (exact 131us-proven baseline geometry)
#define TH 32
#define TW 64
#define SH (TH + 2 * MU)   // 42 staged rows
#define SCW 80             // staged cols = TW + 16 (8-col halo each side)
#define SMS 83             // em LDS row stride (odd -> conflict-free H reads)
#define SVS 81             // V-result LDS row stride (odd -> conflict-free H reads)

__device__ __forceinline__ float fast_rcp(float x) { return __builtin_amdgcn_rcpf(x); }
__device__ __forceinline__ float fast_rsq(float x) { return __builtin_amdgcn_rsqf(x); }

// ---------------------------------------------------------------------------
// Kernel 1 (R11): sobel block-max ONLY — no sf/mag/tang writes (the 16 MB
// s-field round-trip is deleted; pass 1 recomputes sobel inline from x).
// m expressions identical to pass-1's inline sobel -> same gmax bits.
// ---------------------------------------------------------------------------
#define SR 8
__global__ __launch_bounds__(256) void sobel_max(
    const float* __restrict__ x,
    float* __restrict__ block_max)   // 1024
{
    __shared__ float xs[SR + 2][264];
    const int t = threadIdx.x;
    const int w0 = blockIdx.x * 256;
    const int h0 = blockIdx.y * SR;
    const int b = blockIdx.z;
    const size_t plane = (size_t)HH * WW;
    const float* xb = x + (size_t)b * plane;

    for (int i = t; i < (SR + 2) * 66; i += 256) {
        int r = i / 66, c4 = i % 66;
        int g = h0 - 1 + r;
        int gw = w0 - 4 + 4 * c4;
        float4 v = make_float4(0.f, 0.f, 0.f, 0.f);
        if (g >= 0 && g < HH && gw >= 0 && gw < WW)
            v = *(const float4*)(xb + (size_t)g * WW + gw);
        *(float4*)&xs[r][4 * c4] = v;
    }
    __syncthreads();

    float lmax = 0.f;
    const int c = 4 + t;
    #pragma unroll
    for (int k = 0; k < SR; ++k) {
        const float* rT = xs[k], * rM = xs[k + 1], * rB = xs[k + 2];
        float tl = rT[c - 1], tc = rT[c], tr = rT[c + 1];
        float ml = rM[c - 1],             mr = rM[c + 1];
        float bl = rB[c - 1], bc = rB[c], br = rB[c + 1];
        float s0 = (bl - tl) + 2.f * (bc - tc) + (br - tr);   // k
        float s1 = (tr - tl) + 2.f * (mr - ml) + (br - bl);   // k^T
        float m = sqrtf(fmaf(s0, s0, s1 * s1));
        lmax = fmaxf(lmax, m);
    }

    #pragma unroll
    for (int off = 32; off; off >>= 1) lmax = fmaxf(lmax, __shfl_down(lmax, off, 64));
    __shared__ float smax[4];
    if ((t & 63) == 0) smax[t >> 6] = lmax;
    __syncthreads();
    if (t == 0)
        block_max[(blockIdx.z * 128 + blockIdx.y) * 4 + blockIdx.x] =
            fmaxf(fmaxf(smax[0], smax[1]), fmaxf(smax[2], smax[3]));
}

// ---------------------------------------------------------------------------
// Kernel 2: FUSED V+H ETF pass — exact proven compute structure.
// EMPREP=1 (pass 1): tin = x (single-channel). Prologue gmax reduce -> s2.
//   Stage computes SOBEL INLINE per 2-px chunk: 12 clamped scalar x-loads
//   (L1/L2-hot; lanes overlap) -> s0/s1 (expressions identical to sobel_max)
//   -> m -> tang=(-s1,s0)*rcp(m) -> st, em=expf(-s2*m) -> sm. Stage-time
//   VALU proven hidden (R8/R9/R10). OOB px: tang=0, em=1; edge px use
//   zero-padded x via select (exact old xs-staging semantics). After the
//   stage barrier: write interior 32x64 em slice to emw (R9-proven).
// EMPREP=0 (passes 2/3): tin = tang ping-pong, msrc = precomputed em; pure
//   float4 copy-stage (OOB default 1.0). R9/R10-proven bits.
// Weight identity: (tanh(my-mx)+1)/2 == 1/(1 + em_y/em_x).
// LDS 40824 B -> 4 blocks/CU.
// ---------------------------------------------------------------------------
template <int PLANAR_OUT, int EMPREP>
__global__ __launch_bounds__(256, 4) void etf_vh(
    const float* __restrict__ tin,   // (B,H,W): x (pass1) | (B,H,W,2) tang
    float* __restrict__ tout,        // interleaved, or planar (B,2,H,W)
    const float* __restrict__ msrc,  // (B,H,W) precomputed em (passes 2/3)
    float* __restrict__ emw,         // (B,H,W) em out (pass 1)
    const float* __restrict__ block_max)
{
    __shared__ float lds[SH * SCW * 2 + SH * SMS];   // 40824 B
    __shared__ float smax[4];
    float* st  = lds;                 // staged tang, float2/px, row stride 160 floats
    float* sm  = lds + SH * SCW * 2;  // staged em, row stride SMS
    float* sv0 = lds;                 // V results plane 0 (aliases st)
    float* sv1 = lds + TH * SVS;      // V results plane 1

    const int t = threadIdx.x;

    // XCD-aware swizzle (proven neutral; keeps per-XCD slab L2-resident)
    int lin = blockIdx.x + 16 * blockIdx.y + 512 * blockIdx.z;   // grid 16x32xBB
    lin = (lin & 7) * ((16 * 32 * BB) >> 3) + (lin >> 3);
    const int w0 = (lin & 15) * TW;
    const int h0 = ((lin >> 4) & 31) * TH;
    const int b  = lin >> 9;

    const size_t plane = (size_t)HH * WW;

    // ---- prologue (pass 1 only): gmax reduce -> s2
    float s2 = 0.f;
    if (EMPREP) {
        float m = fmaxf(fmaxf(block_max[t], block_max[t + 256]),
                        fmaxf(block_max[t + 512], block_max[t + 768]));
        #pragma unroll
        for (int off = 32; off; off >>= 1) m = fmaxf(m, __shfl_down(m, off, 64));
        if ((t & 63) == 0) smax[t >> 6] = m;
        __syncthreads();
        const float gm = fmaxf(fmaxf(smax[0], smax[1]), fmaxf(smax[2], smax[3]));
        s2 = 2.f * fast_rcp(gm);
    }

    // ---- stage
    if (EMPREP) {
        // inline sobel: x -> tang (st) + em (sm), 42x40 2-px chunks
        const float* xb = tin + (size_t)b * plane;
        for (int i = t; i < SH * 40; i += 256) {
            int r = i / 40, c4 = i % 40;
            int g = h0 - MU + r;
            int gw = w0 - 8 + 2 * c4;
            float* td = &st[r * (SCW * 2) + 4 * c4];
            float* ed = &sm[r * SMS + 2 * c4];
            float xv[3][4];
            #pragma unroll
            for (int r2 = 0; r2 < 3; ++r2) {
                int row = g - 1 + r2;
                bool rok = (row >= 0) && (row < HH);
                const float* rp = xb + (size_t)(rok ? row : 0) * WW;
                #pragma unroll
                for (int c2 = 0; c2 < 4; ++c2) {
                    int col = gw - 1 + c2;
                    bool cok = (col >= 0) && (col < WW);
                    float v = rp[cok ? col : 0];
                    xv[r2][c2] = (rok && cok) ? v : 0.f;
                }
            }
            const bool rin = (g >= 0) && (g < HH);
            #pragma unroll
            for (int p = 0; p < 2; ++p) {
                int j = 1 + p;
                if (rin && (gw + p >= 0) && (gw + p < WW)) {
                    float tl = xv[0][j - 1], tc = xv[0][j], tr = xv[0][j + 1];
                    float ml = xv[1][j - 1],                mr = xv[1][j + 1];
                    float bl = xv[2][j - 1], bc = xv[2][j], br = xv[2][j + 1];
                    float s0 = (bl - tl) + 2.f * (bc - tc) + (br - tr);   // k
                    float s1 = (tr - tl) + 2.f * (mr - ml) + (br - bl);   // k^T
                    float m  = sqrtf(fmaf(s0, s0, s1 * s1));
                    float iv = (m == 0.f) ? 1.f : fast_rcp(m);
                    td[2 * p]     = -s1 * iv;
                    td[2 * p + 1] =  s0 * iv;
                    ed[p] = __expf(-s2 * m);
                } else {
                    td[2 * p] = 0.f;
                    td[2 * p + 1] = 0.f;
                    ed[p] = 1.f;
                }
            }
        }
    } else {
        // tang 42x40 float4 copy; em 42x20 float4 copy from precomputed em
        const float* tb = tin + 2 * (size_t)b * plane;
        const float* mb = msrc + (size_t)b * plane;
        for (int i = t; i < SH * 40 + SH * 20; i += 256) {
            if (i < SH * 40) {
                int r = i / 40, c4 = i % 40;
                int g = h0 - MU + r;
                int gw = w0 - 8 + 2 * c4;
                float4 v = make_float4(0.f, 0.f, 0.f, 0.f);
                if (g >= 0 && g < HH && gw >= 0 && gw < WW)
                    v = *(const float4*)(tb + 2 * ((size_t)g * WW + gw));
                *(float4*)&st[r * (SCW * 2) + 4 * c4] = v;    // 16B-aligned
            } else {
                int j = i - SH * 40;
                int r = j / 20, c4 = j % 20;
                int g = h0 - MU + r;
                int gw = w0 - 8 + 4 * c4;
                float4 v = make_float4(1.f, 1.f, 1.f, 1.f);   // OOB em = exp(0) = 1
                if (g >= 0 && g < HH && gw >= 0 && gw < WW)
                    v = *(const float4*)(mb + (size_t)g * WW + gw);
                float* dst = &sm[r * SMS + 4 * c4];
                dst[0] = v.x; dst[1] = v.y; dst[2] = v.z; dst[3] = v.w;
            }
        }
    }
    __syncthreads();

    // ---- pass 1: write interior em slice (32x64) to global for passes 2/3.
    // LDS->global, 2 float4/thread; stores drain under the V-read phase.
    if (EMPREP) {
        float* ew = emw + (size_t)b * plane;
        #pragma unroll
        for (int q = 0; q < 2; ++q) {
            int i = t + q * 256;             // 512 float4 chunks = 32 x 16
            int rr = i >> 4, c4 = i & 15;
            const float* s = &sm[(rr + MU) * SMS + 8 + 4 * c4];
            float4 v = make_float4(s[0], s[1], s[2], s[3]);
            *(float4*)&ew[(size_t)(h0 + rr) * WW + (w0 + 4 * c4)] = v;
        }
    }

    // ---- shared register window (reused by V then H phase)
    float r0a[21], r1a[21], rea[21];

    // ---- V phase: 240 threads = 80 cols x 3 row-strips {11,11,10}.
    const int c = t % 80;
    const int strip = t / 80;
    const int vr0row = strip * 11;
    const int Rv = (strip == 2) ? 10 : 11;
    if (t < 240) {
        #pragma unroll
        for (int j = 0; j < 21; ++j) {
            if (j < Rv + 10) {
                float2 v = *(const float2*)&st[((vr0row + j) * SCW + c) * 2];
                r0a[j] = v.x; r1a[j] = v.y;
                rea[j] = sm[(vr0row + j) * SMS + c];
            }
        }
    }
    __syncthreads();          // all st reads done; safe to overwrite via sv alias

    __builtin_amdgcn_s_setprio(1);
    if (t < 240) {
        #pragma unroll
        for (int i = 0; i < 11; ++i) {
            if (i < Rv) {
                float tx0 = r0a[i + 5], tx1 = r1a[i + 5];
                float remx = fast_rcp(rea[i + 5]);
                float a0 = 0.f, a1 = 0.f;
                #pragma unroll
                for (int d = 0; d <= 2 * MU; ++d) {
                    float y0 = r0a[i + d], y1 = r1a[i + d], ey = rea[i + d];
                    float s = fast_rcp(fmaf(ey, remx, 1.f));    // (tanh(my-mx)+1)/2
                    float w = s * fmaf(tx0, y0, tx1 * y1);
                    a0 = fmaf(y0, w, a0);
                    a1 = fmaf(y1, w, a1);
                }
                float n2 = fmaf(a0, a0, a1 * a1);
                float inv = (n2 == 0.f) ? 1.f : fast_rsq(n2);
                sv0[(vr0row + i) * SVS + c] = a0 * inv;
                sv1[(vr0row + i) * SVS + c] = a1 * inv;
            }
        }
    }
    __builtin_amdgcn_s_setprio(0);
    __syncthreads();

    // ---- H phase: lane<->row map (r = t&31, colgroup = t>>5 of 8 cols).
    const int r = t & 31;
    const int cg = t >> 5;
    const int cbase = 8 + cg * 8;            // staged col of first center
    #pragma unroll
    for (int j = 0; j < 18; ++j) {
        int sc = cbase - 5 + j;              // 3..76: always in [0,80)
        r0a[j] = sv0[r * SVS + sc];
        r1a[j] = sv1[r * SVS + sc];
        rea[j] = sm[(r + MU) * SMS + sc];
    }
    __syncthreads();          // all sv reads done; safe to overwrite below

    __builtin_amdgcn_s_setprio(1);
    #pragma unroll
    for (int k = 0; k < 8; ++k) {
        float tx0 = r0a[k + 5], tx1 = r1a[k + 5];
        float remx = fast_rcp(rea[k + 5]);
        float a0 = 0.f, a1 = 0.f;
        #pragma unroll
        for (int d = 0; d <= 2 * MU; ++d) {
            float y0 = r0a[k + d], y1 = r1a[k + d], ey = rea[k + d];
            float s = fast_rcp(fmaf(ey, remx, 1.f));
            float w = s * fmaf(tx0, y0, tx1 * y1);
            a0 = fmaf(y0, w, a0);
            a1 = fmaf(y1, w, a1);
        }
        float n2 = fmaf(a0, a0, a1 * a1);
        float inv = (n2 == 0.f) ? 1.f : fast_rsq(n2);
        sv0[r * SVS + cbase + k] = a0 * inv;    // write to LDS (post-barrier)
        sv1[r * SVS + cbase + k] = a1 * inv;
    }
    __builtin_amdgcn_s_setprio(0);
    __syncthreads();

    // ---- coalesced global writeout (lanes along cols)
    #pragma unroll
    for (int m = 0; m < 8; ++m) {
        int px = t + 256 * m;
        int rr = px >> 6, cc = px & 63;
        float v0 = sv0[rr * SVS + 8 + cc];
        float v1 = sv1[rr * SVS + 8 + cc];
        size_t gi = (size_t)(h0 + rr) * WW + (w0 + cc);
        if (PLANAR_OUT) {
            tout[(size_t)(2 * b)     * plane + gi] = v0;
            tout[(size_t)(2 * b + 1) * plane + gi] = v1;
        } else {
            *(float2*)&tout[2 * ((size_t)b * plane + gi)] = make_float2(v0, v1);
        }
    }
}

extern "C" void kernel_launch(void* const* d_in, const int* in_sizes, int n_in,
                              void* d_out, int out_size, void* d_ws, size_t ws_size,
                              hipStream_t stream)
{
    const float* x = (const float*)d_in[0];   // (2,1,1024,1024) fp32
    char* ws = (char*)d_ws;
    const size_t plane = (size_t)HH * WW;

    float* tfA  = (float*)ws;                                           // 16 MB tang ping A
    float* tfB  = (float*)(ws + sizeof(float) * BB * 2 * plane);        // 16 MB tang ping B
    float* em   = (float*)(ws + sizeof(float) * BB * 4 * plane);        // 8 MB em
    float* block_max = (float*)(ws + sizeof(float) * BB * 5 * plane);   // 1024 floats

    sobel_max<<<dim3(4, 128, BB), 256, 0, stream>>>(x, block_max);

    dim3 g(WW / TW, HH / TH, BB);
    // pass 1: x -> tang+em inline (sobel in stage); passes 2/3 copy-stage
    etf_vh<0, 1><<<g, 256, 0, stream>>>(x, tfA, nullptr, em, block_max);
    etf_vh<0, 0><<<g, 256, 0, stream>>>(tfA, tfB, em, nullptr, nullptr);
    etf_vh<1, 0><<<g, 256, 0, stream>>>(tfB, (float*)d_out, em, nullptr, nullptr);
}

// Round 14
// 129.877 us; speedup vs baseline: 1.0280x; 1.0280x over previous
//
#include <hip/hip_runtime.h>

#define BB 2
#define HH 1024
#define WW 1024
#define MU 5

// fused-pass tile geometry (exact 131us-proven baseline geometry)
#define TH 32
#define TW 64
#define SH (TH + 2 * MU)   // 42 staged rows
#define SCW 80             // staged cols = TW + 16 (8-col halo each side)
#define SMS 83             // em LDS row stride (odd -> conflict-free H reads)
#define SVS 81             // V-result LDS row stride (odd -> conflict-free H reads)

__device__ __forceinline__ float fast_rcp(float x) { return __builtin_amdgcn_rcpf(x); }
__device__ __forceinline__ float fast_rsq(float x) { return __builtin_amdgcn_rsqf(x); }

// ---------------------------------------------------------------------------
// Kernel 1: Sobel -> RAW s-field (B,H,W,2) + block max of |s|.
// (R10-proven: tang/mag/em are pure functions of (s0,s1); pass 1 recomputes
// them in its stage loop from the same bits with the same expressions ->
// bit-identical. R11 lesson: recomputing sobel itself in pass 1 is SLOWER
// than this 16 MB round-trip — 12 scalar loads vs 1 float4 on the stage
// critical path.)
// ---------------------------------------------------------------------------
#define SR 8
__global__ __launch_bounds__(256) void sobel_init(
    const float* __restrict__ x,
    float* __restrict__ sf,          // (B,H,W,2) interleaved RAW (s0,s1)
    float* __restrict__ block_max)   // 1024
{
    __shared__ float xs[SR + 2][264];
    const int t = threadIdx.x;
    const int w0 = blockIdx.x * 256;
    const int h0 = blockIdx.y * SR;
    const int b = blockIdx.z;
    const size_t plane = (size_t)HH * WW;
    const float* xb = x + (size_t)b * plane;

    for (int i = t; i < (SR + 2) * 66; i += 256) {
        int r = i / 66, c4 = i % 66;
        int g = h0 - 1 + r;
        int gw = w0 - 4 + 4 * c4;
        float4 v = make_float4(0.f, 0.f, 0.f, 0.f);
        if (g >= 0 && g < HH && gw >= 0 && gw < WW)
            v = *(const float4*)(xb + (size_t)g * WW + gw);
        *(float4*)&xs[r][4 * c4] = v;
    }
    __syncthreads();

    float lmax = 0.f;
    const int c = 4 + t;
    #pragma unroll
    for (int k = 0; k < SR; ++k) {
        const float* rT = xs[k], * rM = xs[k + 1], * rB = xs[k + 2];
        float tl = rT[c - 1], tc = rT[c], tr = rT[c + 1];
        float ml = rM[c - 1],             mr = rM[c + 1];
        float bl = rB[c - 1], bc = rB[c], br = rB[c + 1];
        float s0 = (bl - tl) + 2.f * (bc - tc) + (br - tr);   // k
        float s1 = (tr - tl) + 2.f * (mr - ml) + (br - bl);   // k^T
        float m = sqrtf(fmaf(s0, s0, s1 * s1));
        size_t gi = (size_t)(h0 + k) * WW + (w0 + t);
        ((float2*)sf)[(size_t)b * plane + gi] = make_float2(s0, s1);
        lmax = fmaxf(lmax, m);
    }

    #pragma unroll
    for (int off = 32; off; off >>= 1) lmax = fmaxf(lmax, __shfl_down(lmax, off, 64));
    __shared__ float smax[4];
    if ((t & 63) == 0) smax[t >> 6] = lmax;
    __syncthreads();
    if (t == 0)
        block_max[(blockIdx.z * 128 + blockIdx.y) * 4 + blockIdx.x] =
            fmaxf(fmaxf(smax[0], smax[1]), fmaxf(smax[2], smax[3]));
}

// ---------------------------------------------------------------------------
// Kernel 2: FUSED V+H ETF pass — exact proven compute structure.
// EMPREP=1 (pass 1): tin = RAW s-field. Prologue gmax reduce -> s2. MERGED
//   stage loop (1680 iters): ONE float4 read (2 px of (s0,s1)) ->
//   m=sqrtf(fmaf(..)), tang=(-s1,s0)*rcp(m) -> st, em=expf(-s2*m) -> sm.
//   (R8/R9/R10: stage-time transcendentals are hidden under stage latency.)
//   After the stage barrier: write interior 32x64 em slice to emw for
//   passes 2/3 (drains under V-read, off critical path).
// EMPREP=0 (passes 2/3): tin = tang ping-pong, msrc = precomputed em; pure
//   float4 copy-stage (OOB default 1.0 = exp(-0)). Proven bits.
// Weight identity: (tanh(my-mx)+1)/2 == 1/(1 + em_y/em_x).
// LDS 40824 B -> 4 blocks/CU.
// ---------------------------------------------------------------------------
template <int PLANAR_OUT, int EMPREP>
__global__ __launch_bounds__(256, 4) void etf_vh(
    const float* __restrict__ tin,   // (B,H,W,2): s-field (pass1) or tang
    float* __restrict__ tout,        // interleaved, or planar (B,2,H,W)
    const float* __restrict__ msrc,  // (B,H,W) precomputed em (passes 2/3)
    float* __restrict__ emw,         // (B,H,W) em out (pass 1)
    const float* __restrict__ block_max)
{
    __shared__ float lds[SH * SCW * 2 + SH * SMS];   // 40824 B
    __shared__ float smax[4];
    float* st  = lds;                 // staged tang, float2/px, row stride 160 floats
    float* sm  = lds + SH * SCW * 2;  // staged em, row stride SMS
    float* sv0 = lds;                 // V results plane 0 (aliases st)
    float* sv1 = lds + TH * SVS;      // V results plane 1

    const int t = threadIdx.x;

    // XCD-aware swizzle (proven neutral; keeps per-XCD slab L2-resident)
    int lin = blockIdx.x + 16 * blockIdx.y + 512 * blockIdx.z;   // grid 16x32xBB
    lin = (lin & 7) * ((16 * 32 * BB) >> 3) + (lin >> 3);
    const int w0 = (lin & 15) * TW;
    const int h0 = ((lin >> 4) & 31) * TH;
    const int b  = lin >> 9;

    const size_t plane = (size_t)HH * WW;
    const float* tb = tin + 2 * (size_t)b * plane;

    // ---- prologue (pass 1 only): gmax reduce -> s2
    float s2 = 0.f;
    if (EMPREP) {
        float m = fmaxf(fmaxf(block_max[t], block_max[t + 256]),
                        fmaxf(block_max[t + 512], block_max[t + 768]));
        #pragma unroll
        for (int off = 32; off; off >>= 1) m = fmaxf(m, __shfl_down(m, off, 64));
        if ((t & 63) == 0) smax[t >> 6] = m;
        __syncthreads();
        const float gm = fmaxf(fmaxf(smax[0], smax[1]), fmaxf(smax[2], smax[3]));
        s2 = 2.f * fast_rcp(gm);
    }

    // ---- stage
    if (EMPREP) {
        // merged: one s-field read -> tang (st) + em (sm), 42x40 chunks
        for (int i = t; i < SH * 40; i += 256) {
            int r = i / 40, c4 = i % 40;
            int g = h0 - MU + r;
            int gw = w0 - 8 + 2 * c4;
            float* td = &st[r * (SCW * 2) + 4 * c4];
            float* ed = &sm[r * SMS + 2 * c4];
            if (g >= 0 && g < HH && gw >= 0 && gw < WW) {
                float4 v = *(const float4*)(tb + 2 * ((size_t)g * WW + gw));
                float m0 = sqrtf(fmaf(v.x, v.x, v.y * v.y));
                float i0 = (m0 == 0.f) ? 1.f : fast_rcp(m0);
                float m1 = sqrtf(fmaf(v.z, v.z, v.w * v.w));
                float i1 = (m1 == 0.f) ? 1.f : fast_rcp(m1);
                *(float4*)td = make_float4(-v.y * i0, v.x * i0, -v.w * i1, v.z * i1);
                ed[0] = __expf(-s2 * m0);
                ed[1] = __expf(-s2 * m1);
            } else {
                *(float4*)td = make_float4(0.f, 0.f, 0.f, 0.f);
                ed[0] = 1.f;
                ed[1] = 1.f;
            }
        }
    } else {
        // tang 42x40 float4 copy; em 42x20 float4 copy from precomputed em
        const float* mb = msrc + (size_t)b * plane;
        for (int i = t; i < SH * 40 + SH * 20; i += 256) {
            if (i < SH * 40) {
                int r = i / 40, c4 = i % 40;
                int g = h0 - MU + r;
                int gw = w0 - 8 + 2 * c4;
                float4 v = make_float4(0.f, 0.f, 0.f, 0.f);
                if (g >= 0 && g < HH && gw >= 0 && gw < WW)
                    v = *(const float4*)(tb + 2 * ((size_t)g * WW + gw));
                *(float4*)&st[r * (SCW * 2) + 4 * c4] = v;    // 16B-aligned
            } else {
                int j = i - SH * 40;
                int r = j / 20, c4 = j % 20;
                int g = h0 - MU + r;
                int gw = w0 - 8 + 4 * c4;
                float4 v = make_float4(1.f, 1.f, 1.f, 1.f);   // OOB em = exp(0) = 1
                if (g >= 0 && g < HH && gw >= 0 && gw < WW)
                    v = *(const float4*)(mb + (size_t)g * WW + gw);
                float* dst = &sm[r * SMS + 4 * c4];
                dst[0] = v.x; dst[1] = v.y; dst[2] = v.z; dst[3] = v.w;
            }
        }
    }
    __syncthreads();

    // ---- pass 1: write interior em slice (32x64) to global for passes 2/3.
    // LDS->global, 2 float4/thread; stores drain under the V-read phase.
    if (EMPREP) {
        float* ew = emw + (size_t)b * plane;
        #pragma unroll
        for (int q = 0; q < 2; ++q) {
            int i = t + q * 256;             // 512 float4 chunks = 32 x 16
            int rr = i >> 4, c4 = i & 15;
            const float* s = &sm[(rr + MU) * SMS + 8 + 4 * c4];
            float4 v = make_float4(s[0], s[1], s[2], s[3]);
            *(float4*)&ew[(size_t)(h0 + rr) * WW + (w0 + 4 * c4)] = v;
        }
    }

    // ---- shared register window (reused by V then H phase)
    float r0a[21], r1a[21], rea[21];

    // ---- V phase: 240 threads = 80 cols x 3 row-strips {11,11,10}.
    const int c = t % 80;
    const int strip = t / 80;
    const int vr0row = strip * 11;
    const int Rv = (strip == 2) ? 10 : 11;
    if (t < 240) {
        #pragma unroll
        for (int j = 0; j < 21; ++j) {
            if (j < Rv + 10) {
                float2 v = *(const float2*)&st[((vr0row + j) * SCW + c) * 2];
                r0a[j] = v.x; r1a[j] = v.y;
                rea[j] = sm[(vr0row + j) * SMS + c];
            }
        }
    }
    __syncthreads();          // all st reads done; safe to overwrite via sv alias

    __builtin_amdgcn_s_setprio(1);
    if (t < 240) {
        #pragma unroll
        for (int i = 0; i < 11; ++i) {
            if (i < Rv) {
                float tx0 = r0a[i + 5], tx1 = r1a[i + 5];
                float remx = fast_rcp(rea[i + 5]);
                float a0 = 0.f, a1 = 0.f;
                #pragma unroll
                for (int d = 0; d <= 2 * MU; ++d) {
                    float y0 = r0a[i + d], y1 = r1a[i + d], ey = rea[i + d];
                    float s = fast_rcp(fmaf(ey, remx, 1.f));    // (tanh(my-mx)+1)/2
                    float w = s * fmaf(tx0, y0, tx1 * y1);
                    a0 = fmaf(y0, w, a0);
                    a1 = fmaf(y1, w, a1);
                }
                float n2 = fmaf(a0, a0, a1 * a1);
                float inv = (n2 == 0.f) ? 1.f : fast_rsq(n2);
                sv0[(vr0row + i) * SVS + c] = a0 * inv;
                sv1[(vr0row + i) * SVS + c] = a1 * inv;
            }
        }
    }
    __builtin_amdgcn_s_setprio(0);
    __syncthreads();

    // ---- H phase: lane<->row map (r = t&31, colgroup = t>>5 of 8 cols).
    const int r = t & 31;
    const int cg = t >> 5;
    const int cbase = 8 + cg * 8;            // staged col of first center
    #pragma unroll
    for (int j = 0; j < 18; ++j) {
        int sc = cbase - 5 + j;              // 3..76: always in [0,80)
        r0a[j] = sv0[r * SVS + sc];
        r1a[j] = sv1[r * SVS + sc];
        rea[j] = sm[(r + MU) * SMS + sc];
    }
    __syncthreads();          // all sv reads done; safe to overwrite below

    __builtin_amdgcn_s_setprio(1);
    #pragma unroll
    for (int k = 0; k < 8; ++k) {
        float tx0 = r0a[k + 5], tx1 = r1a[k + 5];
        float remx = fast_rcp(rea[k + 5]);
        float a0 = 0.f, a1 = 0.f;
        #pragma unroll
        for (int d = 0; d <= 2 * MU; ++d) {
            float y0 = r0a[k + d], y1 = r1a[k + d], ey = rea[k + d];
            float s = fast_rcp(fmaf(ey, remx, 1.f));
            float w = s * fmaf(tx0, y0, tx1 * y1);
            a0 = fmaf(y0, w, a0);
            a1 = fmaf(y1, w, a1);
        }
        float n2 = fmaf(a0, a0, a1 * a1);
        float inv = (n2 == 0.f) ? 1.f : fast_rsq(n2);
        sv0[r * SVS + cbase + k] = a0 * inv;    // write to LDS (post-barrier)
        sv1[r * SVS + cbase + k] = a1 * inv;
    }
    __builtin_amdgcn_s_setprio(0);
    __syncthreads();

    // ---- coalesced global writeout (lanes along cols)
    #pragma unroll
    for (int m = 0; m < 8; ++m) {
        int px = t + 256 * m;
        int rr = px >> 6, cc = px & 63;
        float v0 = sv0[rr * SVS + 8 + cc];
        float v1 = sv1[rr * SVS + 8 + cc];
        size_t gi = (size_t)(h0 + rr) * WW + (w0 + cc);
        if (PLANAR_OUT) {
            tout[(size_t)(2 * b)     * plane + gi] = v0;
            tout[(size_t)(2 * b + 1) * plane + gi] = v1;
        } else {
            *(float2*)&tout[2 * ((size_t)b * plane + gi)] = make_float2(v0, v1);
        }
    }
}

extern "C" void kernel_launch(void* const* d_in, const int* in_sizes, int n_in,
                              void* d_out, int out_size, void* d_ws, size_t ws_size,
                              hipStream_t stream)
{
    const float* x = (const float*)d_in[0];   // (2,1,1024,1024) fp32
    char* ws = (char*)d_ws;
    const size_t plane = (size_t)HH * WW;

    float* tfA  = (float*)ws;                                           // 16 MB: s-field, then tang
    float* tfB  = (float*)(ws + sizeof(float) * BB * 2 * plane);        // 16 MB tang ping-pong
    float* em   = (float*)(ws + sizeof(float) * BB * 4 * plane);        // 8 MB em
    float* block_max = (float*)(ws + sizeof(float) * BB * 5 * plane);   // 1024 floats

    sobel_init<<<dim3(4, 128, BB), 256, 0, stream>>>(x, tfA, block_max);

    dim3 g(WW / TW, HH / TH, BB);
    // pass 1: s-field -> tang+em inline; passes 2/3 copy-stage from em
    etf_vh<0, 1><<<g, 256, 0, stream>>>(tfA, tfB, nullptr, em, block_max);
    etf_vh<0, 0><<<g, 256, 0, stream>>>(tfB, tfA, em, nullptr, nullptr);
    etf_vh<1, 0><<<g, 256, 0, stream>>>(tfA, (float*)d_out, em, nullptr, nullptr);
}